// Round 13
// baseline (201.768 us; speedup 1.0000x reference)
//
#include <hip/hip_runtime.h>
#include <hip/hip_bf16.h>

// MLA absorbed causal attention, MI355X round 17:
//  v15: flash64 occupancy bump. v14's flash64: VALUBusy 43 / MfmaUtil 11 /
//  Occupancy 26% -> latency-bound, 2 WG/CU (LDS 67.6 KB, 3-deep buffers).
//  Flip the trade per m114 (TLP > per-WG pipeline depth): 2-deep K/V buffers
//  (50 KB total) -> 3 WG/CU = 24 waves; round close = vmcnt(0)+barrier;
//  __launch_bounds__(512,6). All other kernels byte-identical to v14 (passed).
// fp32 I/O. d_out = [ y (2*2048*1024) | c_kv (2*2048*512) ] fp32.

using bf16 = __hip_bfloat16;
using u32  = unsigned int;
using short8 = __attribute__((ext_vector_type(8))) short;   // 8 bf16 (4 VGPRs)
using f4     = __attribute__((ext_vector_type(4))) float;   // 16x16 accumulator

static constexpr int kB  = 2;
static constexpr int kT  = 2048;
static constexpr int kC  = 1024;
static constexpr int kNH = 16;
static constexpr int kL  = 512;

__device__ inline u32 f2bf2(float a, float b) {
  bf16 ha = __float2bfloat16(a), hb = __float2bfloat16(b);
  unsigned short ua, ub;
  __builtin_memcpy(&ua, &ha, 2);
  __builtin_memcpy(&ub, &hb, 2);
  return (u32)ua | ((u32)ub << 16);
}
__device__ inline unsigned short f2bf(float x) {
  bf16 h = __float2bfloat16(x);
  unsigned short u; __builtin_memcpy(&u, &h, 2);
  return u;
}
__device__ inline short8 frag_ld(const void* p) {   // 16B aligned -> ds/global b128
  short8 r; __builtin_memcpy(&r, p, 16); return r;
}
// async global->LDS DMA, 16 B/lane. dest = wave-uniform base + lane*16.
__device__ inline void g2lds16(const bf16* g, bf16* l) {
  __builtin_amdgcn_global_load_lds(
      (const __attribute__((address_space(1))) u32*)g,
      (__attribute__((address_space(3))) u32*)l, 16, 0, 0);
}

// ---- merged: flat casts (id<6656) + transpose-casts (id>=6656) ----
__global__ __launch_bounds__(256)
void casts_merged(const float* __restrict__ x,   const float* __restrict__ wdq,
                  const float* __restrict__ wuq, const float* __restrict__ wdkv,
                  const float* __restrict__ wo,  const float* __restrict__ wuk,
                  const float* __restrict__ wuv,
                  bf16* __restrict__ xb,   bf16* __restrict__ wdqb,
                  bf16* __restrict__ wuqb, bf16* __restrict__ wdkvb,
                  bf16* __restrict__ wob,
                  bf16* __restrict__ uqT, bf16* __restrict__ ukT,
                  bf16* __restrict__ uvT, bf16* __restrict__ dqT)
{
  __shared__ float s[32][33];
  const int id = blockIdx.x;
  if (id < 6656) {
    long i = (long)(id * 256 + threadIdx.x) * 4;
    const float* sp; bf16* d; long off;
    if      (i < 4194304) { sp = x;    d = xb;    off = i; }
    else if (i < 4718592) { sp = wdq;  d = wdqb;  off = i - 4194304; }
    else if (i < 5242880) { sp = wuq;  d = wuqb;  off = i - 4718592; }
    else if (i < 5767168) { sp = wdkv; d = wdkvb; off = i - 5242880; }
    else                  { sp = wo;   d = wob;   off = i - 5767168; }
    float4 v = *(const float4*)(sp + off);
    *(uint2*)((u32*)d + off / 2) = make_uint2(f2bf2(v.x, v.y), f2bf2(v.z, v.w));
  } else {
    const int t = id - 6656;
    const int z = t >> 10, xy = t & 1023;
    const float* src = z == 0 ? wuq : z == 1 ? wuk : z == 2 ? wuv : wdq;
    bf16* dst        = z == 0 ? uqT : z == 1 ? ukT : z == 2 ? uvT : dqT;
    const int R = (z == 3) ? 512 : 1024, C = (z == 3) ? 1024 : 512;
    const int r0 = (xy & 31) * 32, c0 = (xy >> 5) * 32;
    if (r0 >= R || c0 >= C) return;
    const int xl = threadIdx.x & 31, y = threadIdx.x >> 5;   // y: 0..7
#pragma unroll
    for (int i = 0; i < 4; ++i)
      s[y*4 + i][xl] = src[(long)(r0 + y*4 + i) * C + c0 + xl];
    __syncthreads();
    unsigned short* dp = (unsigned short*)dst;
#pragma unroll
    for (int i = 0; i < 4; ++i)
      dp[(long)(c0 + y*4 + i) * R + r0 + xl] = f2bf(s[xl][y*4 + i]);
  }
}

// strided upcast: ckv half of qc [4096][1024] cols 512..1023 -> fp32 [4096][512]
__global__ __launch_bounds__(256)
void upcast_kernel(const bf16* __restrict__ qc, float* __restrict__ dst)
{
  int i = (blockIdx.x * 256 + threadIdx.x) * 4;
  if (i < 2097152) {
    int row = i >> 9, col = i & 511;
    uint2 v = *(const uint2*)((const u32*)(qc + (long)row * 1024 + 512 + col));
    float4 o;
    o.x = __uint_as_float(v.x << 16);
    o.y = __uint_as_float(v.x & 0xffff0000u);
    o.z = __uint_as_float(v.y << 16);
    o.w = __uint_as_float(v.y & 0xffff0000u);
    *(float4*)(dst + i) = o;
  }
}

// ---------------------------------------------------------------------------
// NT MFMA GEMM, 64-tile (round-3 proven): C[m][n]=alpha*sum_k A[m][k]B[n][k].
// ---------------------------------------------------------------------------
template<typename TCe>
__global__ __launch_bounds__(256)
void mm_nt(const bf16* __restrict__ A, int lda, long aHi, long aLo,
           const bf16* __restrict__ Bm, int ldb, long bHi, long bLo,
           TCe* __restrict__ Cm, int ldc, long cHi, long cLo,
           int K, float alpha)
{
  const int z = blockIdx.z;
  A  += (long)(z >> 4) * aHi + (long)(z & 15) * aLo;
  Bm += (long)(z >> 4) * bHi + (long)(z & 15) * bLo;
  Cm += (long)(z >> 4) * cHi + (long)(z & 15) * cLo;

  __shared__ __align__(16) bf16 As[64][72];
  __shared__ __align__(16) bf16 Bs[64][72];

  const int tid = threadIdx.x;
  const int w = tid >> 6, lane = tid & 63;
  const int quad = lane >> 4, lp = lane & 15;
  const int m0 = blockIdx.x * 64, n0 = blockIdx.y * 64;
  const int row = tid >> 2, cseg = (tid & 3) * 16;

  f4 acc[4];
#pragma unroll
  for (int i = 0; i < 4; ++i) acc[i] = f4{0.f, 0.f, 0.f, 0.f};

  for (int k0 = 0; k0 < K; k0 += 64) {
    const bf16* ag = A  + (long)(m0 + row) * lda + k0 + cseg;
    const bf16* bg = Bm + (long)(n0 + row) * ldb + k0 + cseg;
    uint4 a0 = *(const uint4*)ag, a1 = *(const uint4*)(ag + 8);
    uint4 b0 = *(const uint4*)bg, b1 = *(const uint4*)(bg + 8);
    __syncthreads();
    *(uint4*)&As[row][cseg] = a0; *(uint4*)&As[row][cseg + 8] = a1;
    *(uint4*)&Bs[row][cseg] = b0; *(uint4*)&Bs[row][cseg + 8] = b1;
    __syncthreads();

    short8 af0 = frag_ld(&As[w*16 + lp][quad * 8]);
    short8 af1 = frag_ld(&As[w*16 + lp][32 + quad * 8]);
#pragma unroll
    for (int nb = 0; nb < 4; ++nb) {
      short8 bf0 = frag_ld(&Bs[nb*16 + lp][quad * 8]);
      short8 bf1 = frag_ld(&Bs[nb*16 + lp][32 + quad * 8]);
      acc[nb] = __builtin_amdgcn_mfma_f32_16x16x32_bf16(af0, bf0, acc[nb], 0, 0, 0);
      acc[nb] = __builtin_amdgcn_mfma_f32_16x16x32_bf16(af1, bf1, acc[nb], 0, 0, 0);
    }
  }
#pragma unroll
  for (int nb = 0; nb < 4; ++nb)
#pragma unroll
    for (int r = 0; r < 4; ++r) {
      float v = alpha * acc[nb][r];
      long off = (long)(m0 + w*16 + quad*4 + r) * ldc + n0 + nb*16 + lp;
      if constexpr (__is_same(TCe, float)) Cm[off] = v;
      else ((unsigned short*)Cm)[off] = f2bf(v);
    }
}

// ---------------------------------------------------------------------------
// mega1: segmented mm_nt body, all segments K=1024, alpha=1, bf16 out.
//  id<1024:  qc = x @ [W_dq;W_dkv]^T   (4096x1024)
//  id<1088:  tmpT = W_ukT @ W_uqT^T    (512x512)   [tmpT[l][q]]
//  id<1216:  v_effT = W_o @ W_uvT^T    (1024x512)  [v_effT[hd][l]]
// ---------------------------------------------------------------------------
__global__ __launch_bounds__(256)
void mega1(const bf16* __restrict__ xb,   const bf16* __restrict__ wdq,
           const bf16* __restrict__ wukT, const bf16* __restrict__ wuqT,
           const bf16* __restrict__ wo,   const bf16* __restrict__ wuvT,
           bf16* __restrict__ qc, bf16* __restrict__ tmpT,
           bf16* __restrict__ v_effT)
{
  const int id = blockIdx.x;
  const bf16 *A, *Bm; bf16* Cm;
  int lda, ldb, ldc, m0, n0;
  if (id < 1024) {
    m0 = (id & 63) * 64; n0 = (id >> 6) * 64;
    A = xb;   lda = 1024; Bm = wdq;  ldb = 1024; Cm = qc;     ldc = 1024;
  } else if (id < 1088) {
    const int t = id - 1024;
    m0 = (t & 7) * 64; n0 = (t >> 3) * 64;
    A = wukT; lda = 1024; Bm = wuqT; ldb = 1024; Cm = tmpT;   ldc = 512;
  } else {
    const int t = id - 1088;
    m0 = (t & 15) * 64; n0 = (t >> 4) * 64;
    A = wo;   lda = 1024; Bm = wuvT; ldb = 1024; Cm = v_effT; ldc = 512;
  }

  __shared__ __align__(16) bf16 As[64][72];
  __shared__ __align__(16) bf16 Bs[64][72];

  const int tid = threadIdx.x;
  const int w = tid >> 6, lane = tid & 63;
  const int quad = lane >> 4, lp = lane & 15;
  const int row = tid >> 2, cseg = (tid & 3) * 16;

  f4 acc[4];
#pragma unroll
  for (int i = 0; i < 4; ++i) acc[i] = f4{0.f, 0.f, 0.f, 0.f};

  for (int k0 = 0; k0 < 1024; k0 += 64) {
    const bf16* ag = A  + (long)(m0 + row) * lda + k0 + cseg;
    const bf16* bg = Bm + (long)(n0 + row) * ldb + k0 + cseg;
    uint4 a0 = *(const uint4*)ag, a1 = *(const uint4*)(ag + 8);
    uint4 b0 = *(const uint4*)bg, b1 = *(const uint4*)(bg + 8);
    __syncthreads();
    *(uint4*)&As[row][cseg] = a0; *(uint4*)&As[row][cseg + 8] = a1;
    *(uint4*)&Bs[row][cseg] = b0; *(uint4*)&Bs[row][cseg + 8] = b1;
    __syncthreads();

    short8 af0 = frag_ld(&As[w*16 + lp][quad * 8]);
    short8 af1 = frag_ld(&As[w*16 + lp][32 + quad * 8]);
#pragma unroll
    for (int nb = 0; nb < 4; ++nb) {
      short8 bf0 = frag_ld(&Bs[nb*16 + lp][quad * 8]);
      short8 bf1 = frag_ld(&Bs[nb*16 + lp][32 + quad * 8]);
      acc[nb] = __builtin_amdgcn_mfma_f32_16x16x32_bf16(af0, bf0, acc[nb], 0, 0, 0);
      acc[nb] = __builtin_amdgcn_mfma_f32_16x16x32_bf16(af1, bf1, acc[nb], 0, 0, 0);
    }
  }
#pragma unroll
  for (int nb = 0; nb < 4; ++nb)
#pragma unroll
    for (int r = 0; r < 4; ++r) {
      long off = (long)(m0 + w*16 + quad*4 + r) * ldc + n0 + nb*16 + lp;
      ((unsigned short*)Cm)[off] = f2bf(acc[nb][r]);
    }
}

// ---------------------------------------------------------------------------
// gemm_multi (v13, passed): 768-WG segment decode, 128x128 tiles, K=512.
//  id<256:   qfull  = q_low @ W_uq^T    (4096x1024), alpha 1
//  id<512:   K_head = ckv @ k_effF^T    (4096x1024), alpha kScale
//  id<768:   V_headT[b] = v_effT @ ckv[b]^T (1024x2048), alpha 1
// ---------------------------------------------------------------------------
__global__ __launch_bounds__(256)
void gemm_multi(const bf16* __restrict__ qc,   const bf16* __restrict__ wuq,
                const bf16* __restrict__ keff, const bf16* __restrict__ veff,
                bf16* __restrict__ qfull, bf16* __restrict__ Kh,
                bf16* __restrict__ Vh, float kScale)
{
  const int id = blockIdx.x;
  const bf16 *A, *Bm; bf16* Cm;
  int lda, ldb, ldc, m0, n0; float alpha;
  if (id < 256) {            // qfull: A=q_low (qc cols 0..511)
    m0 = (id >> 3) * 128; n0 = (id & 7) * 128;
    A = qc;        lda = 1024; Bm = wuq;  ldb = 512;
    Cm = qfull;    ldc = 1024; alpha = 1.0f;
  } else if (id < 512) {     // K_head: A=ckv (qc cols 512..1023)
    const int t = id - 256;
    m0 = (t >> 3) * 128; n0 = (t & 7) * 128;
    A = qc + 512;  lda = 1024; Bm = keff; ldb = 512;
    Cm = Kh;       ldc = 1024; alpha = kScale;
  } else {                   // V_headT per b: A=v_effT, B=ckv[b]
    const int t = id - 512;
    const int b = t >> 7, tt = t & 127;
    m0 = (tt >> 4) * 128; n0 = (tt & 15) * 128;
    A = veff;      lda = 512;
    Bm = qc + (long)b * kT * 1024 + 512; ldb = 1024;
    Cm = Vh + (long)b * 1024 * kT;       ldc = kT; alpha = 1.0f;
  }

  __shared__ __align__(16) bf16 As[128 * 64];          // 16 KB
  __shared__ __align__(16) bf16 Bs[128 * 64];          // 16 KB

  const int tid = threadIdx.x;
  const int w = tid >> 6, lane = tid & 63;
  const int quad = lane >> 4, lp = lane & 15;
  const int wm = w >> 1, wn = w & 1;

  // staging: wave w stages rows [w*32, w*32+32) in 4 chunks of 8 rows.
  const int srow = lane >> 3;                    // 0..7
  const int scol = ((lane & 7) ^ srow) * 8;      // pre-swizzled elem offset
  const bf16* aSrc = A  + (long)(m0 + w * 32 + srow) * lda + scol;
  const bf16* bSrc = Bm + (long)(n0 + w * 32 + srow) * ldb + scol;
  bf16* aDst = As + w * 32 * 64;
  bf16* bDst = Bs + w * 32 * 64;

  f4 acc[4][4];
#pragma unroll
  for (int mi = 0; mi < 4; ++mi)
#pragma unroll
    for (int ni = 0; ni < 4; ++ni) acc[mi][ni] = f4{0.f, 0.f, 0.f, 0.f};

  // frag-read lane constants: row = base + mi*16 + lp -> row&7 = lp&7
  const int swz = lp & 7;
  const int aRow = (wm * 64 + lp) * 64;
  const int bRow = (wn * 64 + lp) * 64;
  const int c0 = (quad       ^ swz) * 8;         // k-seg 0..31
  const int c1 = ((quad + 4) ^ swz) * 8;         // k-seg 32..63

  for (int k0 = 0; k0 < 512; k0 += 64) {
#pragma unroll
    for (int i = 0; i < 4; ++i) {
      g2lds16(aSrc + k0 + (long)(i * 8) * lda, aDst + i * 8 * 64);
      g2lds16(bSrc + k0 + (long)(i * 8) * ldb, bDst + i * 8 * 64);
    }
    asm volatile("s_waitcnt vmcnt(0)" ::: "memory");
    __builtin_amdgcn_s_barrier();

    short8 af0[4], af1[4], bf0[4], bf1[4];
#pragma unroll
    for (int mi = 0; mi < 4; ++mi) {
      af0[mi] = frag_ld(&As[aRow + mi * 1024 + c0]);
      af1[mi] = frag_ld(&As[aRow + mi * 1024 + c1]);
    }
#pragma unroll
    for (int ni = 0; ni < 4; ++ni) {
      bf0[ni] = frag_ld(&Bs[bRow + ni * 1024 + c0]);
      bf1[ni] = frag_ld(&Bs[bRow + ni * 1024 + c1]);
    }
#pragma unroll
    for (int mi = 0; mi < 4; ++mi)
#pragma unroll
      for (int ni = 0; ni < 4; ++ni) {
        acc[mi][ni] = __builtin_amdgcn_mfma_f32_16x16x32_bf16(
            af0[mi], bf0[ni], acc[mi][ni], 0, 0, 0);
        acc[mi][ni] = __builtin_amdgcn_mfma_f32_16x16x32_bf16(
            af1[mi], bf1[ni], acc[mi][ni], 0, 0, 0);
      }
    __builtin_amdgcn_s_barrier();
  }

#pragma unroll
  for (int mi = 0; mi < 4; ++mi)
#pragma unroll
    for (int ni = 0; ni < 4; ++ni)
#pragma unroll
      for (int r = 0; r < 4; ++r) {
        float v = alpha * acc[mi][ni][r];
        long off = (long)(m0 + wm*64 + mi*16 + quad*4 + r) * ldc
                 + n0 + wn*64 + ni*16 + lp;
        ((unsigned short*)Cm)[off] = f2bf(v);
      }
}

// ---------------------------------------------------------------------------
// flash64 v15: balanced 1D grid + DOUBLE-buffered staging, 3 WG/CU.
// LDS 50 KB (Kt[2]+Vt[2]=32K, Pb 18K); round close = vmcnt(0)+barrier;
// the drain hides behind the other two co-resident WGs' compute (m114 TLP).
// K full-width [b][t][h*64+d] (tile stride 64*1024); V_headT [b][hd][t].
// ---------------------------------------------------------------------------
__global__ __launch_bounds__(512, 6)
void flash64(const bf16* __restrict__ qfull, const bf16* __restrict__ Kh,
             const bf16* __restrict__ VhT, float* __restrict__ y)
{
  const int id = blockIdx.x;
  const int j = id & 255, hi2 = id >> 8;
  const int h = j >> 4, sl = j & 15;
  const int s = hi2 ? (15 - sl) : sl;
  const int b = hi2;
  const int tid = threadIdx.x;
  const int w = tid >> 6, lane = tid & 63;
  const int quad = lane >> 4, lp = lane & 15;

  __shared__ __align__(16) bf16 Kt[2][64 * 64];        // 16 KB
  __shared__ __align__(16) bf16 Vt[2][64 * 64];        // 16 KB
  __shared__ __align__(16) bf16 Pb[8][16 * 72];        // 18 KB

  bf16* Pw = &Pb[w][0];

  const long bh = (long)b * kNH + h;
  const int q0 = s * 128 + w * 16;

  // Q fragments (B-operand): [q=lp][d-seg]; d 0..31 -> qf0, 32..63 -> qf1
  const bf16* qp = qfull + ((long)b * kT + q0 + lp) * kC + h * 64 + quad * 8;
  const short8 qf0 = frag_ld(qp);
  const short8 qf1 = frag_ld(qp + 32);

  // staging: lane stages tile row rk = w*8 + lane/8, phys block = lane&7;
  // source pre-swizzled so LDS phys block pb holds logical pb ^ (rk&7).
  const int rk = w * 8 + (lane >> 3), blk = lane & 7;
  const int soff = ((blk ^ (rk & 7)) * 8);
  const bf16* kSrc = Kh + ((long)b * kT + rk) * kC + h * 64 + soff;  // full-width
  const bf16* vSrc = VhT + (bh * 64 + rk) * (long)kT + soff;

  // A-frag lane constants: addr = row*64 + ((blkL)^(lp&7))*8, blkL = ds*4+quad
  const int swz = lp & 7;
  const int lp64 = lp * 64;
  const int B0 = ((0 + quad) ^ swz) * 8;               // d/k seg 0..31
  const int B1 = ((4 + quad) ^ swz) * 8;               // d/k seg 32..63

  const int tmaxw = 2 * s + ((w >> 2) ? 1 : 0);
  const int nt = 2 * s + 2;

  f4 O0 = f4{0,0,0,0}, O1 = f4{0,0,0,0}, O2 = f4{0,0,0,0}, O3 = f4{0,0,0,0};
  float m_r = -3e38f, l_r = 0.f;

  // prologue: stage tile 0 into buffer 0 (also drains qf loads)
  g2lds16(kSrc, &Kt[0][w * 512]);
  g2lds16(vSrc, &Vt[0][w * 512]);
  asm volatile("s_waitcnt vmcnt(0)" ::: "memory");
  __builtin_amdgcn_s_barrier();
  __builtin_amdgcn_sched_barrier(0);

  for (int t = 0; t < nt; ++t) {
    const int bf = t & 1;
    if (t + 1 < nt) {                     // stage t+1 into other buffer
      g2lds16(kSrc + (long)(t + 1) * 65536, &Kt[bf ^ 1][w * 512]);
      g2lds16(vSrc + (t + 1) * 64,          &Vt[bf ^ 1][w * 512]);
    }

    if (t <= tmaxw) {
      // ---- QK: S^T[key][q], 4 key-tiles x 2 d-steps ----
      const bf16* KB = &Kt[bf][0];
      f4 s0 = f4{0,0,0,0}, s1 = f4{0,0,0,0}, s2 = f4{0,0,0,0}, s3 = f4{0,0,0,0};
      {
        short8 a;
        a = frag_ld(KB +    0 + lp64 + B0); s0 = __builtin_amdgcn_mfma_f32_16x16x32_bf16(a, qf0, s0, 0, 0, 0);
        a = frag_ld(KB +    0 + lp64 + B1); s0 = __builtin_amdgcn_mfma_f32_16x16x32_bf16(a, qf1, s0, 0, 0, 0);
        a = frag_ld(KB + 1024 + lp64 + B0); s1 = __builtin_amdgcn_mfma_f32_16x16x32_bf16(a, qf0, s1, 0, 0, 0);
        a = frag_ld(KB + 1024 + lp64 + B1); s1 = __builtin_amdgcn_mfma_f32_16x16x32_bf16(a, qf1, s1, 0, 0, 0);
        a = frag_ld(KB + 2048 + lp64 + B0); s2 = __builtin_amdgcn_mfma_f32_16x16x32_bf16(a, qf0, s2, 0, 0, 0);
        a = frag_ld(KB + 2048 + lp64 + B1); s2 = __builtin_amdgcn_mfma_f32_16x16x32_bf16(a, qf1, s2, 0, 0, 0);
        a = frag_ld(KB + 3072 + lp64 + B0); s3 = __builtin_amdgcn_mfma_f32_16x16x32_bf16(a, qf0, s3, 0, 0, 0);
        a = frag_ld(KB + 3072 + lp64 + B1); s3 = __builtin_amdgcn_mfma_f32_16x16x32_bf16(a, qf1, s3, 0, 0, 0);
      }

      // ---- causal mask (diagonal round): key = 64t + kt*16 + quad*4 + r ----
      if (t == tmaxw) {
        const int kb = t * 64, q = q0 + lp;
#pragma unroll
        for (int r = 0; r < 4; ++r) {
          if (kb +      quad * 4 + r > q) s0[r] = -3e38f;
          if (kb + 16 + quad * 4 + r > q) s1[r] = -3e38f;
          if (kb + 32 + quad * 4 + r > q) s2[r] = -3e38f;
          if (kb + 48 + quad * 4 + r > q) s3[r] = -3e38f;
        }
      }

      // ---- online softmax (q = lp lane-local; cross-quad shfl), defer-max --
      float tm = fmaxf(fmaxf(fmaxf(s0[0], s0[1]), fmaxf(s0[2], s0[3])),
                       fmaxf(fmaxf(s1[0], s1[1]), fmaxf(s1[2], s1[3])));
      tm = fmaxf(tm, fmaxf(fmaxf(fmaxf(s2[0], s2[1]), fmaxf(s2[2], s2[3])),
                           fmaxf(fmaxf(s3[0], s3[1]), fmaxf(s3[2], s3[3]))));
      tm = fmaxf(tm, __shfl_xor(tm, 16, 64));
      tm = fmaxf(tm, __shfl_xor(tm, 32, 64));
      if (__ballot(tm > m_r + 12.0f)) {
        float mn = fmaxf(m_r, tm);
        float al = exp2f(m_r - mn);
        l_r *= al; m_r = mn;
#pragma unroll
        for (int jj = 0; jj < 4; ++jj) {
          O0[jj] *= al; O1[jj] *= al; O2[jj] *= al; O3[jj] *= al;
        }
      }
      float p0[4], p1[4], p2[4], p3[4], rs = 0.f;
#pragma unroll
      for (int r = 0; r < 4; ++r) {
        p0[r] = exp2f(s0[r] - m_r); p1[r] = exp2f(s1[r] - m_r);
        p2[r] = exp2f(s2[r] - m_r); p3[r] = exp2f(s3[r] - m_r);
        rs += p0[r] + p1[r] + p2[r] + p3[r];
      }
      rs += __shfl_xor(rs, 16, 64);
      rs += __shfl_xor(rs, 32, 64);
      l_r += rs;

      // ---- P -> per-wave LDS [q=lp][key], unswizzled, row pad 72 ----
      {
        bf16* pr = Pw + lp * 72 + quad * 4;
        *(uint2*)(pr)      = make_uint2(f2bf2(p0[0], p0[1]), f2bf2(p0[2], p0[3]));
        *(uint2*)(pr + 16) = make_uint2(f2bf2(p1[0], p1[1]), f2bf2(p1[2], p1[3]));
        *(uint2*)(pr + 32) = make_uint2(f2bf2(p2[0], p2[1]), f2bf2(p2[2], p2[3]));
        *(uint2*)(pr + 48) = make_uint2(f2bf2(p3[0], p3[1]), f2bf2(p3[2], p3[3]));
      }
      asm volatile("s_waitcnt lgkmcnt(0)" ::: "memory");
      short8 pb0 = frag_ld(Pw + lp * 72 + quad * 8);        // keys 0..31 seg
      short8 pb1 = frag_ld(Pw + lp * 72 + 32 + quad * 8);   // keys 32..63 seg

      // ---- PV: O^T[d][q] += V^T * P, 4 d-tiles x 2 k-steps ----
      const bf16* VB = &Vt[bf][0];
      {
        short8 a;
        a = frag_ld(VB +    0 + lp64 + B0); O0 = __builtin_amdgcn_mfma_f32_16x16x32_bf16(a, pb0, O0, 0, 0, 0);
        a = frag_ld(VB +    0 + lp64 + B1); O0 = __builtin_amdgcn_mfma_f32_16x16x32_bf16(a, pb1, O0, 0, 0, 0);
        a = frag_ld(VB + 1024 + lp64 + B0); O1 = __builtin_amdgcn_mfma_f32_16x16x32_bf16(a, pb0, O1, 0, 0, 0);
        a = frag_ld(VB + 1024 + lp64 + B1); O1 = __builtin_amdgcn_mfma_f32_16x16x32_bf16(a, pb1, O1, 0, 0, 0);
        a = frag_ld(VB + 2048 + lp64 + B0); O2 = __builtin_amdgcn_mfma_f32_16x16x32_bf16(a, pb0, O2, 0, 0, 0);
        a = frag_ld(VB + 2048 + lp64 + B1); O2 = __builtin_amdgcn_mfma_f32_16x16x32_bf16(a, pb1, O2, 0, 0, 0);
        a = frag_ld(VB + 3072 + lp64 + B0); O3 = __builtin_amdgcn_mfma_f32_16x16x32_bf16(a, pb0, O3, 0, 0, 0);
        a = frag_ld(VB + 3072 + lp64 + B1); O3 = __builtin_amdgcn_mfma_f32_16x16x32_bf16(a, pb1, O3, 0, 0, 0);
      }
    }

    // round close: all reads of buf bf done; t+1 staging landed (vmcnt 0).
    // With 3 WG/CU the drain hides behind the other WGs' compute.
    asm volatile("s_waitcnt vmcnt(0)" ::: "memory");
    __builtin_amdgcn_s_barrier();
    __builtin_amdgcn_sched_barrier(0);
  }

  // ---- epilogue: y[q][h*64+d] = O^T * (1/l) — lane-local, direct fp32 ----
  {
    const float inv = 1.0f / l_r;
    float* yp = y + ((long)b * kT + q0 + lp) * kC + h * 64 + quad * 4;
    *(float4*)(yp +  0) = float4{O0[0]*inv, O0[1]*inv, O0[2]*inv, O0[3]*inv};
    *(float4*)(yp + 16) = float4{O1[0]*inv, O1[1]*inv, O1[2]*inv, O1[3]*inv};
    *(float4*)(yp + 32) = float4{O2[0]*inv, O2[1]*inv, O2[2]*inv, O2[3]*inv};
    *(float4*)(yp + 48) = float4{O3[0]*inv, O3[1]*inv, O3[2]*inv, O3[3]*inv};
  }
}

// ---------------------------------------------------------------------------
extern "C" void kernel_launch(void* const* d_in, const int* in_sizes, int n_in,
                              void* d_out, int out_size, void* d_ws, size_t ws_size,
                              hipStream_t stream)
{
  const float* x     = (const float*)d_in[0];
  const float* W_dq  = (const float*)d_in[1];
  const float* W_uq  = (const float*)d_in[2];
  const float* W_dkv = (const float*)d_in[3];
  const float* W_uk  = (const float*)d_in[4];
  const float* W_uv  = (const float*)d_in[5];
  const float* W_o   = (const float*)d_in[6];

  float* y_out   = (float*)d_out;
  float* ckv_out = y_out + (long)kB * kT * kC;

  // workspace layout (~54 MB)
  char* ws = (char*)d_ws;
  bf16* qc      = (bf16*)(ws + 0);           //  8 MB [4096][q_low(512)|ckv(512)]
  bf16* qfullb  = (bf16*)(ws + 8388608);     //  8 MB
  bf16* K_head  = (bf16*)(ws + 16777216);    //  8 MB (B,T,NH*64) full-width
  bf16* V_headT = (bf16*)(ws + 25165824);    //  8 MB (B,NH*64,T)
  bf16* xb      = (bf16*)(ws + 33554432);    //  8 MB
  bf16* W_dqb   = (bf16*)(ws + 41943040);    //  1 MB  } contiguous pair:
  bf16* W_dkvb  = (bf16*)(ws + 42991616);    //  1 MB  } [W_dq; W_dkv] 1024 rows
  bf16* W_uqb   = (bf16*)(ws + 44040192);    //  1 MB
  bf16* W_ob    = (bf16*)(ws + 45088768);    //  2 MB
  bf16* W_uqTb  = (bf16*)(ws + 47185920);    //  1 MB
  bf16* W_ukTb  = (bf16*)(ws + 48234496);    //  1 MB
  bf16* W_uvTb  = (bf16*)(ws + 49283072);    //  1 MB
  bf16* W_dqTb  = (bf16*)(ws + 50331648);    //  1 MB
  bf16* tmpT    = (bf16*)(ws + 51380224);    // 0.5 MB
  bf16* k_effF  = (bf16*)(ws + 51904512);    //  1 MB (1024 hd x 512 l)
  bf16* v_effT  = (bf16*)(ws + 52953088);    //  1 MB (1024 hd x 512 l)

  const dim3 blk(256);
  const float kScale = 0.125f * 1.44269504088896f;   // 1/sqrt(64) * log2(e)

  // L1: all casts + transpose-casts (one launch)
  casts_merged<<<dim3(10752), blk, 0, stream>>>(
      x, W_dq, W_uq, W_dkv, W_o, W_uk, W_uv,
      xb, W_dqb, W_uqb, W_dkvb, W_ob,
      W_uqTb, W_ukTb, W_uvTb, W_dqTb);

  // L2: qc + tmpT + v_effT (one 1216-WG launch; preps hide under qc)
  mega1<<<dim3(1216), blk, 0, stream>>>(
      xb, W_dqb, W_ukTb, W_uqTb, W_ob, W_uvTb, qc, tmpT, v_effT);

  // L3: k_effF[hd][l] = W_dqT @ tmpT^T (depends on tmpT)
  mm_nt<bf16><<<dim3(16, 8, 1), blk, 0, stream>>>(
      W_dqTb, 512, 0, 0, tmpT, 512, 0, 0, k_effF, 512, 0, 0, 512, 1.0f);

  // L4: qfull + K_head + V_headT in one 768-WG launch (3 WG/CU)
  gemm_multi<<<dim3(768), blk, 0, stream>>>(
      qc, W_uqb, k_effF, v_effT, qfullb, K_head, V_headT, kScale);

  // L5: flash, y fp32 direct, balanced 1D grid, 3 WG/CU
  flash64<<<dim3(512), dim3(512), 0, stream>>>(
      qfullb, K_head, V_headT, y_out);

  // L6: fp32 c_kv output tail (strided from qc)
  upcast_kernel<<<dim3(2048), blk, 0, stream>>>(qc, ckv_out);

  (void)in_sizes; (void)n_in; (void)out_size; (void)ws_size;
}

// Round 15
// 186.972 us; speedup vs baseline: 1.0791x; 1.0791x over previous
//
#include <hip/hip_runtime.h>
#include <hip/hip_bf16.h>

// MLA absorbed causal attention, MI355X round 18 (resubmit after infra fail):
//  v16: flash64 concurrency fix. v15's occupancy stayed 25% because the grid
//  (512 WGs) capped residency at 2 WG/CU and the (s,15-s) pairing left CUs
//  running ONE 8-wave WG after the short stripe finished. Now: 256-thread WGs
//  (4 waves, 64 queries), grid 1024 big-first -> LDS 42 KB = 3 WG/CU with
//  backfill (12 waves/CU sustained). Per-wave compute identical; uniform
//  tmaxw = qblk for all waves. mega1 qc-ckv tiles also write fp32 ckv_out
//  (upcast launch deleted). Launches 6 -> 5.
// fp32 I/O. d_out = [ y (2*2048*1024) | c_kv (2*2048*512) ] fp32.

using bf16 = __hip_bfloat16;
using u32  = unsigned int;
using short8 = __attribute__((ext_vector_type(8))) short;   // 8 bf16 (4 VGPRs)
using f4     = __attribute__((ext_vector_type(4))) float;   // 16x16 accumulator

static constexpr int kB  = 2;
static constexpr int kT  = 2048;
static constexpr int kC  = 1024;
static constexpr int kNH = 16;
static constexpr int kL  = 512;

__device__ inline u32 f2bf2(float a, float b) {
  bf16 ha = __float2bfloat16(a), hb = __float2bfloat16(b);
  unsigned short ua, ub;
  __builtin_memcpy(&ua, &ha, 2);
  __builtin_memcpy(&ub, &hb, 2);
  return (u32)ua | ((u32)ub << 16);
}
__device__ inline unsigned short f2bf(float x) {
  bf16 h = __float2bfloat16(x);
  unsigned short u; __builtin_memcpy(&u, &h, 2);
  return u;
}
__device__ inline short8 frag_ld(const void* p) {   // 16B aligned -> ds/global b128
  short8 r; __builtin_memcpy(&r, p, 16); return r;
}
// async global->LDS DMA, 16 B/lane. dest = wave-uniform base + lane*16.
__device__ inline void g2lds16(const bf16* g, bf16* l) {
  __builtin_amdgcn_global_load_lds(
      (const __attribute__((address_space(1))) u32*)g,
      (__attribute__((address_space(3))) u32*)l, 16, 0, 0);
}

// ---- merged: flat casts (id<6656) + transpose-casts (id>=6656) ----
__global__ __launch_bounds__(256)
void casts_merged(const float* __restrict__ x,   const float* __restrict__ wdq,
                  const float* __restrict__ wuq, const float* __restrict__ wdkv,
                  const float* __restrict__ wo,  const float* __restrict__ wuk,
                  const float* __restrict__ wuv,
                  bf16* __restrict__ xb,   bf16* __restrict__ wdqb,
                  bf16* __restrict__ wuqb, bf16* __restrict__ wdkvb,
                  bf16* __restrict__ wob,
                  bf16* __restrict__ uqT, bf16* __restrict__ ukT,
                  bf16* __restrict__ uvT, bf16* __restrict__ dqT)
{
  __shared__ float s[32][33];
  const int id = blockIdx.x;
  if (id < 6656) {
    long i = (long)(id * 256 + threadIdx.x) * 4;
    const float* sp; bf16* d; long off;
    if      (i < 4194304) { sp = x;    d = xb;    off = i; }
    else if (i < 4718592) { sp = wdq;  d = wdqb;  off = i - 4194304; }
    else if (i < 5242880) { sp = wuq;  d = wuqb;  off = i - 4718592; }
    else if (i < 5767168) { sp = wdkv; d = wdkvb; off = i - 5242880; }
    else                  { sp = wo;   d = wob;   off = i - 5767168; }
    float4 v = *(const float4*)(sp + off);
    *(uint2*)((u32*)d + off / 2) = make_uint2(f2bf2(v.x, v.y), f2bf2(v.z, v.w));
  } else {
    const int t = id - 6656;
    const int z = t >> 10, xy = t & 1023;
    const float* src = z == 0 ? wuq : z == 1 ? wuk : z == 2 ? wuv : wdq;
    bf16* dst        = z == 0 ? uqT : z == 1 ? ukT : z == 2 ? uvT : dqT;
    const int R = (z == 3) ? 512 : 1024, C = (z == 3) ? 1024 : 512;
    const int r0 = (xy & 31) * 32, c0 = (xy >> 5) * 32;
    if (r0 >= R || c0 >= C) return;
    const int xl = threadIdx.x & 31, y = threadIdx.x >> 5;   // y: 0..7
#pragma unroll
    for (int i = 0; i < 4; ++i)
      s[y*4 + i][xl] = src[(long)(r0 + y*4 + i) * C + c0 + xl];
    __syncthreads();
    unsigned short* dp = (unsigned short*)dst;
#pragma unroll
    for (int i = 0; i < 4; ++i)
      dp[(long)(c0 + y*4 + i) * R + r0 + xl] = f2bf(s[xl][y*4 + i]);
  }
}

// ---------------------------------------------------------------------------
// NT MFMA GEMM, 64-tile (round-3 proven): C[m][n]=alpha*sum_k A[m][k]B[n][k].
// ---------------------------------------------------------------------------
template<typename TCe>
__global__ __launch_bounds__(256)
void mm_nt(const bf16* __restrict__ A, int lda, long aHi, long aLo,
           const bf16* __restrict__ Bm, int ldb, long bHi, long bLo,
           TCe* __restrict__ Cm, int ldc, long cHi, long cLo,
           int K, float alpha)
{
  const int z = blockIdx.z;
  A  += (long)(z >> 4) * aHi + (long)(z & 15) * aLo;
  Bm += (long)(z >> 4) * bHi + (long)(z & 15) * bLo;
  Cm += (long)(z >> 4) * cHi + (long)(z & 15) * cLo;

  __shared__ __align__(16) bf16 As[64][72];
  __shared__ __align__(16) bf16 Bs[64][72];

  const int tid = threadIdx.x;
  const int w = tid >> 6, lane = tid & 63;
  const int quad = lane >> 4, lp = lane & 15;
  const int m0 = blockIdx.x * 64, n0 = blockIdx.y * 64;
  const int row = tid >> 2, cseg = (tid & 3) * 16;

  f4 acc[4];
#pragma unroll
  for (int i = 0; i < 4; ++i) acc[i] = f4{0.f, 0.f, 0.f, 0.f};

  for (int k0 = 0; k0 < K; k0 += 64) {
    const bf16* ag = A  + (long)(m0 + row) * lda + k0 + cseg;
    const bf16* bg = Bm + (long)(n0 + row) * ldb + k0 + cseg;
    uint4 a0 = *(const uint4*)ag, a1 = *(const uint4*)(ag + 8);
    uint4 b0 = *(const uint4*)bg, b1 = *(const uint4*)(bg + 8);
    __syncthreads();
    *(uint4*)&As[row][cseg] = a0; *(uint4*)&As[row][cseg + 8] = a1;
    *(uint4*)&Bs[row][cseg] = b0; *(uint4*)&Bs[row][cseg + 8] = b1;
    __syncthreads();

    short8 af0 = frag_ld(&As[w*16 + lp][quad * 8]);
    short8 af1 = frag_ld(&As[w*16 + lp][32 + quad * 8]);
#pragma unroll
    for (int nb = 0; nb < 4; ++nb) {
      short8 bf0 = frag_ld(&Bs[nb*16 + lp][quad * 8]);
      short8 bf1 = frag_ld(&Bs[nb*16 + lp][32 + quad * 8]);
      acc[nb] = __builtin_amdgcn_mfma_f32_16x16x32_bf16(af0, bf0, acc[nb], 0, 0, 0);
      acc[nb] = __builtin_amdgcn_mfma_f32_16x16x32_bf16(af1, bf1, acc[nb], 0, 0, 0);
    }
  }
#pragma unroll
  for (int nb = 0; nb < 4; ++nb)
#pragma unroll
    for (int r = 0; r < 4; ++r) {
      float v = alpha * acc[nb][r];
      long off = (long)(m0 + w*16 + quad*4 + r) * ldc + n0 + nb*16 + lp;
      if constexpr (__is_same(TCe, float)) Cm[off] = v;
      else ((unsigned short*)Cm)[off] = f2bf(v);
    }
}

// ---------------------------------------------------------------------------
// mega1: segmented mm_nt body, all segments K=1024, alpha=1, bf16 out.
//  id<1024:  qc = x @ [W_dq;W_dkv]^T   (4096x1024); ckv-half tiles (n0>=512)
//            ALSO write fp32 ckv_out directly (upcast launch deleted).
//  id<1088:  tmpT = W_ukT @ W_uqT^T    (512x512)   [tmpT[l][q]]
//  id<1216:  v_effT = W_o @ W_uvT^T    (1024x512)  [v_effT[hd][l]]
// ---------------------------------------------------------------------------
__global__ __launch_bounds__(256)
void mega1(const bf16* __restrict__ xb,   const bf16* __restrict__ wdq,
           const bf16* __restrict__ wukT, const bf16* __restrict__ wuqT,
           const bf16* __restrict__ wo,   const bf16* __restrict__ wuvT,
           bf16* __restrict__ qc, bf16* __restrict__ tmpT,
           bf16* __restrict__ v_effT, float* __restrict__ ckv_out)
{
  const int id = blockIdx.x;
  const bf16 *A, *Bm; bf16* Cm;
  int lda, ldb, ldc, m0, n0;
  bool wckv = false;
  if (id < 1024) {
    m0 = (id & 63) * 64; n0 = (id >> 6) * 64;
    A = xb;   lda = 1024; Bm = wdq;  ldb = 1024; Cm = qc;     ldc = 1024;
    wckv = (n0 >= 512);
  } else if (id < 1088) {
    const int t = id - 1024;
    m0 = (t & 7) * 64; n0 = (t >> 3) * 64;
    A = wukT; lda = 1024; Bm = wuqT; ldb = 1024; Cm = tmpT;   ldc = 512;
  } else {
    const int t = id - 1088;
    m0 = (t & 15) * 64; n0 = (t >> 4) * 64;
    A = wo;   lda = 1024; Bm = wuvT; ldb = 1024; Cm = v_effT; ldc = 512;
  }

  __shared__ __align__(16) bf16 As[64][72];
  __shared__ __align__(16) bf16 Bs[64][72];

  const int tid = threadIdx.x;
  const int w = tid >> 6, lane = tid & 63;
  const int quad = lane >> 4, lp = lane & 15;
  const int row = tid >> 2, cseg = (tid & 3) * 16;

  f4 acc[4];
#pragma unroll
  for (int i = 0; i < 4; ++i) acc[i] = f4{0.f, 0.f, 0.f, 0.f};

  for (int k0 = 0; k0 < 1024; k0 += 64) {
    const bf16* ag = A  + (long)(m0 + row) * lda + k0 + cseg;
    const bf16* bg = Bm + (long)(n0 + row) * ldb + k0 + cseg;
    uint4 a0 = *(const uint4*)ag, a1 = *(const uint4*)(ag + 8);
    uint4 b0 = *(const uint4*)bg, b1 = *(const uint4*)(bg + 8);
    __syncthreads();
    *(uint4*)&As[row][cseg] = a0; *(uint4*)&As[row][cseg + 8] = a1;
    *(uint4*)&Bs[row][cseg] = b0; *(uint4*)&Bs[row][cseg + 8] = b1;
    __syncthreads();

    short8 af0 = frag_ld(&As[w*16 + lp][quad * 8]);
    short8 af1 = frag_ld(&As[w*16 + lp][32 + quad * 8]);
#pragma unroll
    for (int nb = 0; nb < 4; ++nb) {
      short8 bf0 = frag_ld(&Bs[nb*16 + lp][quad * 8]);
      short8 bf1 = frag_ld(&Bs[nb*16 + lp][32 + quad * 8]);
      acc[nb] = __builtin_amdgcn_mfma_f32_16x16x32_bf16(af0, bf0, acc[nb], 0, 0, 0);
      acc[nb] = __builtin_amdgcn_mfma_f32_16x16x32_bf16(af1, bf1, acc[nb], 0, 0, 0);
    }
  }
#pragma unroll
  for (int nb = 0; nb < 4; ++nb)
#pragma unroll
    for (int r = 0; r < 4; ++r) {
      float v = acc[nb][r];
      const int rr = m0 + w*16 + quad*4 + r;
      long off = (long)rr * ldc + n0 + nb*16 + lp;
      ((unsigned short*)Cm)[off] = f2bf(v);
      if (wckv)
        ckv_out[(long)rr * 512 + (n0 - 512) + nb*16 + lp] = v;
    }
}

// ---------------------------------------------------------------------------
// gemm_multi (v13, passed): 768-WG segment decode, 128x128 tiles, K=512.
//  id<256:   qfull  = q_low @ W_uq^T    (4096x1024), alpha 1
//  id<512:   K_head = ckv @ k_effF^T    (4096x1024), alpha kScale
//  id<768:   V_headT[b] = v_effT @ ckv[b]^T (1024x2048), alpha 1
// ---------------------------------------------------------------------------
__global__ __launch_bounds__(256)
void gemm_multi(const bf16* __restrict__ qc,   const bf16* __restrict__ wuq,
                const bf16* __restrict__ keff, const bf16* __restrict__ veff,
                bf16* __restrict__ qfull, bf16* __restrict__ Kh,
                bf16* __restrict__ Vh, float kScale)
{
  const int id = blockIdx.x;
  const bf16 *A, *Bm; bf16* Cm;
  int lda, ldb, ldc, m0, n0; float alpha;
  if (id < 256) {            // qfull: A=q_low (qc cols 0..511)
    m0 = (id >> 3) * 128; n0 = (id & 7) * 128;
    A = qc;        lda = 1024; Bm = wuq;  ldb = 512;
    Cm = qfull;    ldc = 1024; alpha = 1.0f;
  } else if (id < 512) {     // K_head: A=ckv (qc cols 512..1023)
    const int t = id - 256;
    m0 = (t >> 3) * 128; n0 = (t & 7) * 128;
    A = qc + 512;  lda = 1024; Bm = keff; ldb = 512;
    Cm = Kh;       ldc = 1024; alpha = kScale;
  } else {                   // V_headT per b: A=v_effT, B=ckv[b]
    const int t = id - 512;
    const int b = t >> 7, tt = t & 127;
    m0 = (tt >> 4) * 128; n0 = (tt & 15) * 128;
    A = veff;      lda = 512;
    Bm = qc + (long)b * kT * 1024 + 512; ldb = 1024;
    Cm = Vh + (long)b * 1024 * kT;       ldc = kT; alpha = 1.0f;
  }

  __shared__ __align__(16) bf16 As[128 * 64];          // 16 KB
  __shared__ __align__(16) bf16 Bs[128 * 64];          // 16 KB

  const int tid = threadIdx.x;
  const int w = tid >> 6, lane = tid & 63;
  const int quad = lane >> 4, lp = lane & 15;
  const int wm = w >> 1, wn = w & 1;

  // staging: wave w stages rows [w*32, w*32+32) in 4 chunks of 8 rows.
  const int srow = lane >> 3;                    // 0..7
  const int scol = ((lane & 7) ^ srow) * 8;      // pre-swizzled elem offset
  const bf16* aSrc = A  + (long)(m0 + w * 32 + srow) * lda + scol;
  const bf16* bSrc = Bm + (long)(n0 + w * 32 + srow) * ldb + scol;
  bf16* aDst = As + w * 32 * 64;
  bf16* bDst = Bs + w * 32 * 64;

  f4 acc[4][4];
#pragma unroll
  for (int mi = 0; mi < 4; ++mi)
#pragma unroll
    for (int ni = 0; ni < 4; ++ni) acc[mi][ni] = f4{0.f, 0.f, 0.f, 0.f};

  // frag-read lane constants: row = base + mi*16 + lp -> row&7 = lp&7
  const int swz = lp & 7;
  const int aRow = (wm * 64 + lp) * 64;
  const int bRow = (wn * 64 + lp) * 64;
  const int c0 = (quad       ^ swz) * 8;         // k-seg 0..31
  const int c1 = ((quad + 4) ^ swz) * 8;         // k-seg 32..63

  for (int k0 = 0; k0 < 512; k0 += 64) {
#pragma unroll
    for (int i = 0; i < 4; ++i) {
      g2lds16(aSrc + k0 + (long)(i * 8) * lda, aDst + i * 8 * 64);
      g2lds16(bSrc + k0 + (long)(i * 8) * ldb, bDst + i * 8 * 64);
    }
    asm volatile("s_waitcnt vmcnt(0)" ::: "memory");
    __builtin_amdgcn_s_barrier();

    short8 af0[4], af1[4], bf0[4], bf1[4];
#pragma unroll
    for (int mi = 0; mi < 4; ++mi) {
      af0[mi] = frag_ld(&As[aRow + mi * 1024 + c0]);
      af1[mi] = frag_ld(&As[aRow + mi * 1024 + c1]);
    }
#pragma unroll
    for (int ni = 0; ni < 4; ++ni) {
      bf0[ni] = frag_ld(&Bs[bRow + ni * 1024 + c0]);
      bf1[ni] = frag_ld(&Bs[bRow + ni * 1024 + c1]);
    }
#pragma unroll
    for (int mi = 0; mi < 4; ++mi)
#pragma unroll
      for (int ni = 0; ni < 4; ++ni) {
        acc[mi][ni] = __builtin_amdgcn_mfma_f32_16x16x32_bf16(
            af0[mi], bf0[ni], acc[mi][ni], 0, 0, 0);
        acc[mi][ni] = __builtin_amdgcn_mfma_f32_16x16x32_bf16(
            af1[mi], bf1[ni], acc[mi][ni], 0, 0, 0);
      }
    __builtin_amdgcn_s_barrier();
  }

#pragma unroll
  for (int mi = 0; mi < 4; ++mi)
#pragma unroll
    for (int ni = 0; ni < 4; ++ni)
#pragma unroll
      for (int r = 0; r < 4; ++r) {
        float v = alpha * acc[mi][ni][r];
        long off = (long)(m0 + wm*64 + mi*16 + quad*4 + r) * ldc
                 + n0 + wn*64 + ni*16 + lp;
        ((unsigned short*)Cm)[off] = f2bf(v);
      }
}

// ---------------------------------------------------------------------------
// flash64 v16: 256-thread WGs (4 waves, 64 queries), grid 1024 big-first.
// id: qblk = 31 - (id>>5) (big stripes dispatch first -> backfill);
// bh = id&31 -> b = bh>>4, h = bh&15. Wave w owns q0 = qblk*64 + w*16.
// All waves share tmaxw = qblk; nt = qblk+1 rounds of 64 keys.
// LDS 42 KB (Kt[2]+Vt[2] 32K + Pb 9K) -> 3 WG/CU; double-buffered staging,
// round close = vmcnt(0)+barrier (drain hides behind 2 other resident WGs).
// Each wave stages 16 tile rows (2 DMAs per buffer per K/V).
// K full-width [b][t][h*64+d]; V_headT [b][hd][t]. XOR-swizzled tiles.
// ---------------------------------------------------------------------------
__global__ __launch_bounds__(256, 3)
void flash64(const bf16* __restrict__ qfull, const bf16* __restrict__ Kh,
             const bf16* __restrict__ VhT, float* __restrict__ y)
{
  const int id = blockIdx.x;
  const int qblk = 31 - (id >> 5);
  const int bh = id & 31;
  const int b = bh >> 4, h = bh & 15;
  const int tid = threadIdx.x;
  const int w = tid >> 6, lane = tid & 63;
  const int quad = lane >> 4, lp = lane & 15;

  __shared__ __align__(16) bf16 Kt[2][64 * 64];        // 16 KB
  __shared__ __align__(16) bf16 Vt[2][64 * 64];        // 16 KB
  __shared__ __align__(16) bf16 Pb[4][16 * 72];        //  9 KB

  bf16* Pw = &Pb[w][0];

  const long bhl = (long)b * kNH + h;
  const int q0 = qblk * 64 + w * 16;

  // Q fragments (B-operand): [q=lp][d-seg]; d 0..31 -> qf0, 32..63 -> qf1
  const bf16* qp = qfull + ((long)b * kT + q0 + lp) * kC + h * 64 + quad * 8;
  const short8 qf0 = frag_ld(qp);
  const short8 qf1 = frag_ld(qp + 32);

  // staging: wave w covers tile rows [w*16, w*16+16) via 2 DMAs per buffer.
  // lane -> rows rk and rk+8; phys block = lane&7, source pre-swizzled.
  const int rk = w * 16 + (lane >> 3), blk = lane & 7;
  const int soff = ((blk ^ (rk & 7)) * 8);             // (rk+8)&7 == rk&7
  const bf16* kSrc = Kh + ((long)b * kT + rk) * kC + h * 64 + soff;
  const bf16* vSrc = VhT + (bhl * 64 + rk) * (long)kT + soff;

  // A-frag lane constants: addr = row*64 + ((blkL)^(lp&7))*8, blkL = ds*4+quad
  const int swz = lp & 7;
  const int lp64 = lp * 64;
  const int B0 = ((0 + quad) ^ swz) * 8;               // d/k seg 0..31
  const int B1 = ((4 + quad) ^ swz) * 8;               // d/k seg 32..63

  const int nt = qblk + 1;                             // uniform for all waves

  f4 O0 = f4{0,0,0,0}, O1 = f4{0,0,0,0}, O2 = f4{0,0,0,0}, O3 = f4{0,0,0,0};
  float m_r = -3e38f, l_r = 0.f;

  // prologue: stage tile 0 into buffer 0 (also drains qf loads)
  g2lds16(kSrc,            &Kt[0][w * 1024]);
  g2lds16(kSrc + 8 * kC,   &Kt[0][w * 1024 + 512]);
  g2lds16(vSrc,            &Vt[0][w * 1024]);
  g2lds16(vSrc + 8 * kT,   &Vt[0][w * 1024 + 512]);
  asm volatile("s_waitcnt vmcnt(0)" ::: "memory");
  __builtin_amdgcn_s_barrier();
  __builtin_amdgcn_sched_barrier(0);

  for (int t = 0; t < nt; ++t) {
    const int bf = t & 1;
    if (t + 1 < nt) {                     // stage t+1 into other buffer
      const bf16* k1 = kSrc + (long)(t + 1) * 65536;   // 64 rows * 1024
      const bf16* v1 = vSrc + (t + 1) * 64;
      g2lds16(k1,          &Kt[bf ^ 1][w * 1024]);
      g2lds16(k1 + 8 * kC, &Kt[bf ^ 1][w * 1024 + 512]);
      g2lds16(v1,          &Vt[bf ^ 1][w * 1024]);
      g2lds16(v1 + 8 * kT, &Vt[bf ^ 1][w * 1024 + 512]);
    }

    {
      // ---- QK: S^T[key][q], 4 key-tiles x 2 d-steps ----
      const bf16* KB = &Kt[bf][0];
      f4 s0 = f4{0,0,0,0}, s1 = f4{0,0,0,0}, s2 = f4{0,0,0,0}, s3 = f4{0,0,0,0};
      {
        short8 a;
        a = frag_ld(KB +    0 + lp64 + B0); s0 = __builtin_amdgcn_mfma_f32_16x16x32_bf16(a, qf0, s0, 0, 0, 0);
        a = frag_ld(KB +    0 + lp64 + B1); s0 = __builtin_amdgcn_mfma_f32_16x16x32_bf16(a, qf1, s0, 0, 0, 0);
        a = frag_ld(KB + 1024 + lp64 + B0); s1 = __builtin_amdgcn_mfma_f32_16x16x32_bf16(a, qf0, s1, 0, 0, 0);
        a = frag_ld(KB + 1024 + lp64 + B1); s1 = __builtin_amdgcn_mfma_f32_16x16x32_bf16(a, qf1, s1, 0, 0, 0);
        a = frag_ld(KB + 2048 + lp64 + B0); s2 = __builtin_amdgcn_mfma_f32_16x16x32_bf16(a, qf0, s2, 0, 0, 0);
        a = frag_ld(KB + 2048 + lp64 + B1); s2 = __builtin_amdgcn_mfma_f32_16x16x32_bf16(a, qf1, s2, 0, 0, 0);
        a = frag_ld(KB + 3072 + lp64 + B0); s3 = __builtin_amdgcn_mfma_f32_16x16x32_bf16(a, qf0, s3, 0, 0, 0);
        a = frag_ld(KB + 3072 + lp64 + B1); s3 = __builtin_amdgcn_mfma_f32_16x16x32_bf16(a, qf1, s3, 0, 0, 0);
      }

      // ---- causal mask (diagonal round): key = 64t + kt*16 + quad*4 + r ----
      if (t == qblk) {
        const int kb = t * 64, q = q0 + lp;
#pragma unroll
        for (int r = 0; r < 4; ++r) {
          if (kb +      quad * 4 + r > q) s0[r] = -3e38f;
          if (kb + 16 + quad * 4 + r > q) s1[r] = -3e38f;
          if (kb + 32 + quad * 4 + r > q) s2[r] = -3e38f;
          if (kb + 48 + quad * 4 + r > q) s3[r] = -3e38f;
        }
      }

      // ---- online softmax (q = lp lane-local; cross-quad shfl), defer-max --
      float tm = fmaxf(fmaxf(fmaxf(s0[0], s0[1]), fmaxf(s0[2], s0[3])),
                       fmaxf(fmaxf(s1[0], s1[1]), fmaxf(s1[2], s1[3])));
      tm = fmaxf(tm, fmaxf(fmaxf(fmaxf(s2[0], s2[1]), fmaxf(s2[2], s2[3])),
                           fmaxf(fmaxf(s3[0], s3[1]), fmaxf(s3[2], s3[3]))));
      tm = fmaxf(tm, __shfl_xor(tm, 16, 64));
      tm = fmaxf(tm, __shfl_xor(tm, 32, 64));
      if (__ballot(tm > m_r + 12.0f)) {
        float mn = fmaxf(m_r, tm);
        float al = exp2f(m_r - mn);
        l_r *= al; m_r = mn;
#pragma unroll
        for (int jj = 0; jj < 4; ++jj) {
          O0[jj] *= al; O1[jj] *= al; O2[jj] *= al; O3[jj] *= al;
        }
      }
      float p0[4], p1[4], p2[4], p3[4], rs = 0.f;
#pragma unroll
      for (int r = 0; r < 4; ++r) {
        p0[r] = exp2f(s0[r] - m_r); p1[r] = exp2f(s1[r] - m_r);
        p2[r] = exp2f(s2[r] - m_r); p3[r] = exp2f(s3[r] - m_r);
        rs += p0[r] + p1[r] + p2[r] + p3[r];
      }
      rs += __shfl_xor(rs, 16, 64);
      rs += __shfl_xor(rs, 32, 64);
      l_r += rs;

      // ---- P -> per-wave LDS [q=lp][key], unswizzled, row pad 72 ----
      {
        bf16* pr = Pw + lp * 72 + quad * 4;
        *(uint2*)(pr)      = make_uint2(f2bf2(p0[0], p0[1]), f2bf2(p0[2], p0[3]));
        *(uint2*)(pr + 16) = make_uint2(f2bf2(p1[0], p1[1]), f2bf2(p1[2], p1[3]));
        *(uint2*)(pr + 32) = make_uint2(f2bf2(p2[0], p2[1]), f2bf2(p2[2], p2[3]));
        *(uint2*)(pr + 48) = make_uint2(f2bf2(p3[0], p3[1]), f2bf2(p3[2], p3[3]));
      }
      asm volatile("s_waitcnt lgkmcnt(0)" ::: "memory");
      short8 pb0 = frag_ld(Pw + lp * 72 + quad * 8);        // keys 0..31 seg
      short8 pb1 = frag_ld(Pw + lp * 72 + 32 + quad * 8);   // keys 32..63 seg

      // ---- PV: O^T[d][q] += V^T * P, 4 d-tiles x 2 k-steps ----
      const bf16* VB = &Vt[bf][0];
      {
        short8 a;
        a = frag_ld(VB +    0 + lp64 + B0); O0 = __builtin_amdgcn_mfma_f32_16x16x32_bf16(a, pb0, O0, 0, 0, 0);
        a = frag_ld(VB +    0 + lp64 + B1); O0 = __builtin_amdgcn_mfma_f32_16x16x32_bf16(a, pb1, O0, 0, 0, 0);
        a = frag_ld(VB + 1024 + lp64 + B0); O1 = __builtin_amdgcn_mfma_f32_16x16x32_bf16(a, pb0, O1, 0, 0, 0);
        a = frag_ld(VB + 1024 + lp64 + B1); O1 = __builtin_amdgcn_mfma_f32_16x16x32_bf16(a, pb1, O1, 0, 0, 0);
        a = frag_ld(VB + 2048 + lp64 + B0); O2 = __builtin_amdgcn_mfma_f32_16x16x32_bf16(a, pb0, O2, 0, 0, 0);
        a = frag_ld(VB + 2048 + lp64 + B1); O2 = __builtin_amdgcn_mfma_f32_16x16x32_bf16(a, pb1, O2, 0, 0, 0);
        a = frag_ld(VB + 3072 + lp64 + B0); O3 = __builtin_amdgcn_mfma_f32_16x16x32_bf16(a, pb0, O3, 0, 0, 0);
        a = frag_ld(VB + 3072 + lp64 + B1); O3 = __builtin_amdgcn_mfma_f32_16x16x32_bf16(a, pb1, O3, 0, 0, 0);
      }
    }

    // round close: all reads of buf bf done; t+1 staging landed.
    // Drain hides behind the other resident WGs' compute (3 WG/CU).
    asm volatile("s_waitcnt vmcnt(0)" ::: "memory");
    __builtin_amdgcn_s_barrier();
    __builtin_amdgcn_sched_barrier(0);
  }

  // ---- epilogue: y[q][h*64+d] = O^T * (1/l) — lane-local, direct fp32 ----
  {
    const float inv = 1.0f / l_r;
    float* yp = y + ((long)b * kT + q0 + lp) * kC + h * 64 + quad * 4;
    *(float4*)(yp +  0) = float4{O0[0]*inv, O0[1]*inv, O0[2]*inv, O0[3]*inv};
    *(float4*)(yp + 16) = float4{O1[0]*inv, O1[1]*inv, O1[2]*inv, O1[3]*inv};
    *(float4*)(yp + 32) = float4{O2[0]*inv, O2[1]*inv, O2[2]*inv, O2[3]*inv};
    *(float4*)(yp + 48) = float4{O3[0]*inv, O3[1]*inv, O3[2]*inv, O3[3]*inv};
  }
}

// ---------------------------------------------------------------------------
extern "C" void kernel_launch(void* const* d_in, const int* in_sizes, int n_in,
                              void* d_out, int out_size, void* d_ws, size_t ws_size,
                              hipStream_t stream)
{
  const float* x     = (const float*)d_in[0];
  const float* W_dq  = (const float*)d_in[1];
  const float* W_uq  = (const float*)d_in[2];
  const float* W_dkv = (const float*)d_in[3];
  const float* W_uk  = (const float*)d_in[4];
  const float* W_uv  = (const float*)d_in[5];
  const float* W_o   = (const float*)d_in[6];

  float* y_out   = (float*)d_out;
  float* ckv_out = y_out + (long)kB * kT * kC;

  // workspace layout (~54 MB)
  char* ws = (char*)d_ws;
  bf16* qc      = (bf16*)(ws + 0);           //  8 MB [4096][q_low(512)|ckv(512)]
  bf16* qfullb  = (bf16*)(ws + 8388608);     //  8 MB
  bf16* K_head  = (bf16*)(ws + 16777216);    //  8 MB (B,T,NH*64) full-width
  bf16* V_headT = (bf16*)(ws + 25165824);    //  8 MB (B,NH*64,T)
  bf16* xb      = (bf16*)(ws + 33554432);    //  8 MB
  bf16* W_dqb   = (bf16*)(ws + 41943040);    //  1 MB  } contiguous pair:
  bf16* W_dkvb  = (bf16*)(ws + 42991616);    //  1 MB  } [W_dq; W_dkv] 1024 rows
  bf16* W_uqb   = (bf16*)(ws + 44040192);    //  1 MB
  bf16* W_ob    = (bf16*)(ws + 45088768);    //  2 MB
  bf16* W_uqTb  = (bf16*)(ws + 47185920);    //  1 MB
  bf16* W_ukTb  = (bf16*)(ws + 48234496);    //  1 MB
  bf16* W_uvTb  = (bf16*)(ws + 49283072);    //  1 MB
  bf16* W_dqTb  = (bf16*)(ws + 50331648);    //  1 MB
  bf16* tmpT    = (bf16*)(ws + 51380224);    // 0.5 MB
  bf16* k_effF  = (bf16*)(ws + 51904512);    //  1 MB (1024 hd x 512 l)
  bf16* v_effT  = (bf16*)(ws + 52953088);    //  1 MB (1024 hd x 512 l)

  const dim3 blk(256);
  const float kScale = 0.125f * 1.44269504088896f;   // 1/sqrt(64) * log2(e)

  // L1: all casts + transpose-casts (one launch)
  casts_merged<<<dim3(10752), blk, 0, stream>>>(
      x, W_dq, W_uq, W_dkv, W_o, W_uk, W_uv,
      xb, W_dqb, W_uqb, W_dkvb, W_ob,
      W_uqTb, W_ukTb, W_uvTb, W_dqTb);

  // L2: qc + tmpT + v_effT (one 1216-WG launch); ckv fp32 out fused
  mega1<<<dim3(1216), blk, 0, stream>>>(
      xb, W_dqb, W_ukTb, W_uqTb, W_ob, W_uvTb, qc, tmpT, v_effT, ckv_out);

  // L3: k_effF[hd][l] = W_dqT @ tmpT^T (depends on tmpT)
  mm_nt<bf16><<<dim3(16, 8, 1), blk, 0, stream>>>(
      W_dqTb, 512, 0, 0, tmpT, 512, 0, 0, k_effF, 512, 0, 0, 512, 1.0f);

  // L4: qfull + K_head + V_headT in one 768-WG launch (3 WG/CU)
  gemm_multi<<<dim3(768), blk, 0, stream>>>(
      qc, W_uqb, k_effF, v_effT, qfullb, K_head, V_headT, kScale);

  // L5: flash, y fp32 direct, 1024 WGs big-first, 3 WG/CU
  flash64<<<dim3(1024), dim3(256), 0, stream>>>(
      qfullb, K_head, V_headT, y_out);

  (void)in_sizes; (void)n_in; (void)out_size; (void)ws_size;
}